// Round 8
// baseline (279.627 us; speedup 1.0000x reference)
//
#include <hip/hip_runtime.h>
#include <hip/hip_bf16.h>
#include <math.h>
#include <stdint.h>

// ---------- types ----------
typedef __attribute__((ext_vector_type(8))) short short8;     // 8 x bf16 (MFMA A/B frag)
typedef __attribute__((ext_vector_type(4))) float floatx4;    // MFMA C/D frag
typedef __attribute__((ext_vector_type(4))) unsigned short ushort4v;

// ---------- helpers ----------
__device__ __forceinline__ void gload_lds16(const void* g, void* lds) {
    __builtin_amdgcn_global_load_lds(
        (__attribute__((address_space(1))) void*)(g),
        (__attribute__((address_space(3))) void*)(lds), 16, 0, 0);
}
__device__ __forceinline__ float bf16bits_to_f(unsigned short u) {
    union { unsigned int i; float f; } x; x.i = ((unsigned int)u) << 16; return x.f;
}
__device__ __forceinline__ unsigned short f_to_bf16bits(float f) {
    union { float f; unsigned int i; } x; x.f = f;
    unsigned int lsb = (x.i >> 16) & 1u;
    x.i += 0x7fffu + lsb;                      // round-to-nearest-even
    return (unsigned short)(x.i >> 16);
}

// =====================================================================
// One-dispatch fp32->bf16 conversion: Q,K,V (12288 blocks) + W x3 (768) +
// b x3 (3). grid 13059.
// =====================================================================
__global__ __launch_bounds__(256) void conv_all_kernel(
    const float* __restrict__ Q, const float* __restrict__ K, const float* __restrict__ V,
    const float* __restrict__ Wq, const float* __restrict__ Wk, const float* __restrict__ Wv,
    const float* __restrict__ bq, const float* __restrict__ bk, const float* __restrict__ bv,
    unsigned short* __restrict__ qkv,  // 3 slots stride 4194304
    unsigned short* __restrict__ Wo,   // 3 slots stride 262144
    unsigned short* __restrict__ bo)   // 3 slots stride 512
{
    const int gid = blockIdx.x;
    const float* src; unsigned short* dst; int idx;
    if (gid < 12288) {
        const int seg = gid >> 12, blk = gid & 4095;
        src = (seg == 0) ? Q : (seg == 1) ? K : V;
        dst = qkv + (size_t)seg * 4194304;
        idx = (blk * 256 + threadIdx.x) * 4;
    } else if (gid < 13056) {
        const int t = gid - 12288, m = t >> 8, blk = t & 255;
        src = (m == 0) ? Wq : (m == 1) ? Wk : Wv;
        dst = Wo + (size_t)m * 262144;
        idx = (blk * 256 + threadIdx.x) * 4;
    } else {
        const int m = gid - 13056;
        if (threadIdx.x >= 128) return;
        src = (m == 0) ? bq : (m == 1) ? bk : bv;
        dst = bo + (size_t)m * 512;
        idx = threadIdx.x * 4;
    }
    float4 v = *(const float4*)&src[idx];
    ushort4v o;
    o[0] = f_to_bf16bits(v.x); o[1] = f_to_bf16bits(v.y);
    o[2] = f_to_bf16bits(v.z); o[3] = f_to_bf16bits(v.w);
    *(ushort4v*)&dst[idx] = o;
}

// single-input fp32 -> bf16 (small-ws fallback). grid 4096.
__global__ __launch_bounds__(256) void conv1_kernel(
    const float* __restrict__ in, unsigned short* __restrict__ out)
{
    const int idx = (blockIdx.x * 256 + threadIdx.x) * 4;
    float4 v = *(const float4*)&in[idx];
    ushort4v o;
    o[0] = f_to_bf16bits(v.x); o[1] = f_to_bf16bits(v.y);
    o[2] = f_to_bf16bits(v.z); o[3] = f_to_bf16bits(v.w);
    *(ushort4v*)&out[idx] = o;
}

// W/b conversion only (fallback path). grid (257,3).
__global__ __launch_bounds__(256) void conv_wb_kernel(
    const float* __restrict__ Wq, const float* __restrict__ Wk, const float* __restrict__ Wv,
    const float* __restrict__ bq, const float* __restrict__ bk, const float* __restrict__ bv,
    unsigned short* __restrict__ Wo, unsigned short* __restrict__ bo)
{
    const int m = blockIdx.y;
    const float* W = (m == 0) ? Wq : (m == 1) ? Wk : Wv;
    const float* b = (m == 0) ? bq : (m == 1) ? bk : bv;
    if (blockIdx.x < 256) {
        const int idx = (blockIdx.x * 256 + threadIdx.x) * 4;
        float4 v = *(const float4*)&W[idx];
        ushort4v o;
        o[0] = f_to_bf16bits(v.x); o[1] = f_to_bf16bits(v.y);
        o[2] = f_to_bf16bits(v.z); o[3] = f_to_bf16bits(v.w);
        *(ushort4v*)&Wo[(size_t)m * 262144 + idx] = o;
    } else if (threadIdx.x < 128) {
        const int idx = threadIdx.x * 4;
        float4 v = *(const float4*)&b[idx];
        ushort4v o;
        o[0] = f_to_bf16bits(v.x); o[1] = f_to_bf16bits(v.y);
        o[2] = f_to_bf16bits(v.z); o[3] = f_to_bf16bits(v.w);
        *(ushort4v*)&bo[(size_t)m * 512 + idx] = o;
    }
}

// =====================================================================
// Projection: C[m,n] = sum_k X[m,k]*W[n,k] + b[n]. M=8192,N=512,K=512.
// grid (256, nmodes); mode = mode_base + blockIdx.y.
// mode 0: q (scaled), 1: k, 2: v stored in PV-B-frag-native layout:
//   V6 elem(b,d,k) at  b*2097152 + (d>>4)*65536 + (k>>3)*128 + (d&15)*8 + (k&7)
// =====================================================================
__global__ __launch_bounds__(256, 2) void proj_kernel(
    const unsigned short* __restrict__ Xall,
    size_t xstride, int mode_base,
    const unsigned short* __restrict__ Wall,  // 3 slots stride 262144
    const unsigned short* __restrict__ ball,  // 3 slots stride 512
    unsigned short* __restrict__ qbuf,        // [8192,512] pre-scaled
    unsigned short* __restrict__ kbuf,        // [8192,512]
    unsigned short* __restrict__ vTbuf,       // V6 layout, 2*2097152 elems
    float qscale)
{
    __shared__ __align__(16) unsigned short Xs[128 * 64];
    __shared__ __align__(16) unsigned short Ws[128 * 64];

    const int mode = mode_base + blockIdx.y;
    const unsigned short* X = Xall + (size_t)blockIdx.y * xstride;
    const unsigned short* W = Wall + (size_t)mode * 262144;
    const unsigned short* bias = ball + (size_t)mode * 512;

    const int tid = threadIdx.x;
    const int wave = tid >> 6, lane = tid & 63, quad = lane >> 4, l15 = lane & 15;
    const int m0 = (int)(blockIdx.x >> 2) << 7;
    const int n0 = (int)(blockIdx.x & 3) << 7;
    const int mw = (wave >> 1) << 6, nw = (wave & 1) << 6;

    floatx4 acc[4][4];
    #pragma unroll
    for (int i = 0; i < 4; i++)
        #pragma unroll
        for (int j = 0; j < 4; j++) acc[i][j] = floatx4{0.f, 0.f, 0.f, 0.f};

    for (int kt = 0; kt < 512; kt += 64) {
        #pragma unroll
        for (int i = 0; i < 4; i++) {
            const int r0 = wave * 32 + i * 8;
            gload_lds16(X + (size_t)(m0 + r0 + (lane >> 3)) * 512 + kt + (lane & 7) * 8, &Xs[r0 * 64]);
            gload_lds16(W + (size_t)(n0 + r0 + (lane >> 3)) * 512 + kt + (lane & 7) * 8, &Ws[r0 * 64]);
        }
        __syncthreads();
        #pragma unroll
        for (int kk = 0; kk < 64; kk += 32) {
            short8 a[4], b[4];
            #pragma unroll
            for (int i = 0; i < 4; i++) a[i] = *(const short8*)&Xs[(mw + 16 * i + l15) * 64 + kk + quad * 8];
            #pragma unroll
            for (int j = 0; j < 4; j++) b[j] = *(const short8*)&Ws[(nw + 16 * j + l15) * 64 + kk + quad * 8];
            #pragma unroll
            for (int i = 0; i < 4; i++)
                #pragma unroll
                for (int j = 0; j < 4; j++)
                    acc[i][j] = __builtin_amdgcn_mfma_f32_16x16x32_bf16(a[i], b[j], acc[i][j], 0, 0, 0);
        }
        __syncthreads();
    }

    float bfj[4];
    #pragma unroll
    for (int j = 0; j < 4; j++) bfj[j] = bf16bits_to_f(bias[n0 + nw + 16 * j + l15]);

    if (mode < 2) {
        unsigned short* out = (mode == 0) ? qbuf : kbuf;
        const float s = (mode == 0) ? qscale : 1.0f;
        #pragma unroll
        for (int i = 0; i < 4; i++) {
            const int mrow = m0 + mw + 16 * i + quad * 4;   // C/D: row = quad*4+reg
            #pragma unroll
            for (int j = 0; j < 4; j++) {
                const int n = n0 + nw + 16 * j + l15;       // C/D: col = lane&15
                #pragma unroll
                for (int r = 0; r < 4; r++)
                    out[(size_t)(mrow + r) * 512 + n] = f_to_bf16bits((acc[i][j][r] + bfj[j]) * s);
            }
        }
    } else {
        // V6 layout: 4 consecutive keys -> 8B store
        #pragma unroll
        for (int i = 0; i < 4; i++) {
            const int mrow = m0 + mw + 16 * i + quad * 4;
            const int bb = mrow >> 12;
            const int k4 = mrow & 4095;
            const size_t kpart = (size_t)bb * 2097152 + (size_t)(k4 >> 3) * 128 + (k4 & 7);
            #pragma unroll
            for (int j = 0; j < 4; j++) {
                const int n = n0 + nw + 16 * j + l15;
                ushort4v pk;
                #pragma unroll
                for (int r = 0; r < 4; r++) pk[r] = f_to_bf16bits(acc[i][j][r] + bfj[j]);
                *(ushort4v*)&vTbuf[kpart + (size_t)(n >> 4) * 65536 + (n & 15) * 8] = pk;
            }
        }
    }
}

// =====================================================================
// Flash attention v5: S-phase d-split reuse-2.
// Wave (mgrp=w>>1, dh=w&1): computes S-partials for rows [32*mgrp,32*mgrp+32)
// x all 32 keys over d-half [256*dh, 256*dh+256). Each Ks b128 read feeds
// 2 MFMAs (row-groups i2=0,1) -> S-phase LDS reads halve vs v3.
// Partner exchange: wave writes its other-key-half partial (8 f32/lane) to
// Xch, reads partner's, adds in-register, exps its own 16-key half -> Ps.
// PV unchanged: wave w owns d-cols [128w,128w+128), V frags direct from
// global (V6 layout). 3 barriers/iter. denom has 2*NSPLIT slots.
// =====================================================================
template <int NSPLIT>
__global__ __launch_bounds__(256, 2) void attn_kernel(
    const unsigned short* __restrict__ q,    // [8192,512] pre-scaled
    const unsigned short* __restrict__ k,    // [8192,512]
    const unsigned short* __restrict__ vT,   // V6 layout
    unsigned short* __restrict__ num,        // [NSPLIT,8192,512] permuted bf16 partials
    float* __restrict__ denom)               // [2*NSPLIT,8192]
{
    constexpr int TK  = 32;
    constexpr int KST = 520;   // 512 + 8 pad
    constexpr int PST = 40;    // 32 + 8 pad
    __shared__ __align__(16) unsigned short Ks[TK * KST];       // 33.3 KB
    __shared__ __align__(16) unsigned short Ps[64 * PST];       // 5 KB
    __shared__ __align__(16) float Xch[2][2][2][64][4];         // [mgrp][c][i2][lane] 8 KB

    const int tid = threadIdx.x;
    const int wave = tid >> 6, lane = tid & 63, quad = lane >> 4, l15 = lane & 15;
    const int mgrp = wave >> 1, dh = wave & 1;
    const int bid = blockIdx.x;
    const int sp   = bid & (NSPLIT - 1);
    const int qblk = bid / NSPLIT;
    const int bb = qblk >> 6;              // batch
    const int q0 = (qblk & 63) << 6;       // q-tile start within batch
    const size_t rowbase = (size_t)bb * 4096 + q0;

    // Q fragments: rows 32*mgrp + 16*i2 + l15, d in [256*dh, 256*dh+256)
    // qf[i2*8 + t], t = d-step (32 each)
    short8 qf[16];
    {
        const unsigned short* qbase = q + (rowbase + 32 * mgrp + l15) * 512 + dh * 256;
        #pragma unroll
        for (int i2 = 0; i2 < 2; i2++)
            #pragma unroll
            for (int t = 0; t < 8; t++)
                qf[i2 * 8 + t] = *(const short8*)&qbase[i2 * 16 * 512 + t * 32 + quad * 8];
    }

    floatx4 oacc[4][8];                    // rows 16i+quad*4+r, cols 128*wave+16c+l15
    #pragma unroll
    for (int i = 0; i < 4; i++)
        #pragma unroll
        for (int c = 0; c < 8; c++) oacc[i][c] = floatx4{0.f, 0.f, 0.f, 0.f};
    float dsum[2][4];                      // [i2][r] partial denom (16 keys of this wave)
    #pragma unroll
    for (int i2 = 0; i2 < 2; i2++)
        #pragma unroll
        for (int r = 0; r < 4; r++) dsum[i2][r] = 0.f;

    const unsigned short* kb = k + (size_t)bb * 4096 * 512;
    const unsigned short* vbase = vT + (size_t)bb * 2097152
                                + (size_t)(8 * wave) * 65536 + quad * 128 + l15 * 8;

    const int jbeg = sp * (4096 / NSPLIT);
    const int jend = jbeg + (4096 / NSPLIT);
    for (int j0 = jbeg; j0 < jend; j0 += TK) {
        // --- stage K tile (32 rows x 512) async ---
        #pragma unroll
        for (int r = 0; r < 8; r++) {
            const int row = wave * 8 + r;                       // one 1KB row per issue
            gload_lds16(kb + (size_t)(j0 + row) * 512 + lane * 8, &Ks[row * KST]);
        }
        __syncthreads();   // B1: K staged (implicit vmcnt0)

        // --- V fragments: coalesced 1KB loads, land during S-phase ---
        short8 vf[8];
        #pragma unroll
        for (int c = 0; c < 8; c++)
            vf[c] = *(const short8*)&vbase[(size_t)c * 65536 + (j0 << 4)];

        // --- S-partials: 32 rows x 32 keys over this wave's d-half ---
        floatx4 sacc[2][2];  // [i2][c]
        sacc[0][0] = sacc[0][1] = sacc[1][0] = sacc[1][1] = floatx4{0.f, 0.f, 0.f, 0.f};
        #pragma unroll
        for (int t = 0; t < 8; t++) {
            #pragma unroll
            for (int c = 0; c < 2; c++) {
                short8 b = *(const short8*)&Ks[(c * 16 + l15) * KST + dh * 256 + t * 32 + quad * 8];
                sacc[0][c] = __builtin_amdgcn_mfma_f32_16x16x32_bf16(qf[t],     b, sacc[0][c], 0, 0, 0);
                sacc[1][c] = __builtin_amdgcn_mfma_f32_16x16x32_bf16(qf[8 + t], b, sacc[1][c], 0, 0, 0);
            }
        }

        // --- exchange: write other-key-half partial, read partner's ---
        *(floatx4*)&Xch[mgrp][1 - dh][0][lane][0] = sacc[0][1 - dh];
        *(floatx4*)&Xch[mgrp][1 - dh][1][lane][0] = sacc[1][1 - dh];
        __syncthreads();   // B2: partials visible
        {
            floatx4 p0 = *(const floatx4*)&Xch[mgrp][dh][0][lane][0];
            floatx4 p1 = *(const floatx4*)&Xch[mgrp][dh][1][lane][0];
            #pragma unroll
            for (int r = 0; r < 4; r++) { sacc[0][dh][r] += p0[r]; sacc[1][dh][r] += p1[r]; }
        }

        // --- exp own 16-key half, write Ps ---
        #pragma unroll
        for (int i2 = 0; i2 < 2; i2++) {
            #pragma unroll
            for (int r = 0; r < 4; r++) {
                const float p = __expf(fminf(sacc[i2][dh][r], 30.0f));
                const unsigned short pb = f_to_bf16bits(p);
                dsum[i2][r] += bf16bits_to_f(pb);
                Ps[(32 * mgrp + 16 * i2 + quad * 4 + r) * PST + dh * 16 + l15] = pb;
            }
        }
        __syncthreads();   // B3: Ps complete before cross-wave A-frag reads

        // --- O[0:64][128w:128w+128] += P @ V (A from LDS, B from regs) ---
        // no 4th barrier: next B1/B2 order Ks-DMA and Xch/Ps hazards
        short8 ap[4];
        #pragma unroll
        for (int i = 0; i < 4; i++) ap[i] = *(const short8*)&Ps[(16 * i + l15) * PST + quad * 8];
        #pragma unroll
        for (int c = 0; c < 8; c++) {
            #pragma unroll
            for (int i = 0; i < 4; i++)
                oacc[i][c] = __builtin_amdgcn_mfma_f32_16x16x32_bf16(ap[i], vf[c], oacc[i][c], 0, 0, 0);
        }
    }

    // denom: reduce each (i2,r) row-partial across the 16 l15 lanes
    #pragma unroll
    for (int i2 = 0; i2 < 2; i2++) {
        #pragma unroll
        for (int r = 0; r < 4; r++) {
            float v = dsum[i2][r];
            v += __shfl_xor(v, 1);
            v += __shfl_xor(v, 2);
            v += __shfl_xor(v, 4);
            v += __shfl_xor(v, 8);
            if (l15 == 0) {
                const size_t row = rowbase + 32 * mgrp + 16 * i2 + quad * 4 + r;
                denom[(size_t)(sp * 2 + dh) * 8192 + row] = v;
            }
        }
    }

    // store bf16 numerator partials, permuted: [row][wave][l15][c] -> b128
    #pragma unroll
    for (int i = 0; i < 4; i++) {
        #pragma unroll
        for (int r = 0; r < 4; r++) {
            const size_t row = rowbase + 16 * i + quad * 4 + r;
            short8 pk;
            #pragma unroll
            for (int c = 0; c < 8; c++) pk[c] = (short)f_to_bf16bits(oacc[i][c][r]);
            *(short8*)&num[((size_t)sp * 8192 + row) * 512 + wave * 128 + l15 * 8] = pk;
        }
    }
}

// =====================================================================
// Combine: out = (sum_sp num) / (sum over 2*nsplit denom slots), fp32 out.
// thread = (srow, w, l15); reads permuted num as b128.
// =====================================================================
__global__ __launch_bounds__(256) void combine_kernel(
    const unsigned short* __restrict__ num,
    const float* __restrict__ denom,
    float* __restrict__ out,
    int nsplit)
{
    const int gid = blockIdx.x * 256 + threadIdx.x;
    const int srow = gid >> 6;            // 0..8191
    const int sub = gid & 63;
    const int w = sub >> 4, l15 = sub & 15;
    float s[8];
    #pragma unroll
    for (int e = 0; e < 8; e++) s[e] = 0.f;
    float den = 0.f;
    for (int sp = 0; sp < 2 * nsplit; sp++)
        den += denom[(size_t)sp * 8192 + srow];
    for (int sp = 0; sp < nsplit; sp++) {
        short8 v = *(const short8*)(num + ((size_t)sp * 8192 + srow) * 512 + w * 128 + l15 * 8);
        #pragma unroll
        for (int e = 0; e < 8; e++) s[e] += bf16bits_to_f((unsigned short)v[e]);
    }
    const float inv = 1.0f / den;
    float* op = out + (size_t)srow * 512 + w * 128 + l15;
    #pragma unroll
    for (int c = 0; c < 8; c++) op[16 * c] = s[c] * inv;
}

// =====================================================================
extern "C" void kernel_launch(void* const* d_in, const int* in_sizes, int n_in,
                              void* d_out, int out_size, void* d_ws, size_t ws_size,
                              hipStream_t stream)
{
    (void)in_sizes; (void)n_in; (void)out_size;
    const float* Qin = (const float*)d_in[0];
    const float* Kin = (const float*)d_in[1];
    const float* Vin = (const float*)d_in[2];
    const float* Wq  = (const float*)d_in[3];
    const float* bq  = (const float*)d_in[4];
    const float* Wk  = (const float*)d_in[5];
    const float* bk  = (const float*)d_in[6];
    const float* Wv  = (const float*)d_in[7];
    const float* bv  = (const float*)d_in[8];

    const size_t M   = (size_t)8192 * 512;   // 4,194,304 elems
    const size_t WS_ = (size_t)512 * 512;

    // ws layout (bf16 elems): [slotA: conv inputs / num partials][qs][ks][vT][Wc x3][bc x3][denom f32 x 2ns]
    auto need = [&](size_t sa, int ns) -> size_t {
        return (sa + 3 * M) * 2 + 3 * WS_ * 2 + 3 * 512 * 2 + 64 + (size_t)ns * 2 * 8192 * 4;
    };
    int nsplit; size_t sa; bool batched;
    if      (ws_size >= need(4 * M, 4)) { nsplit = 4; sa = 4 * M; batched = true; }
    else if (ws_size >= need(3 * M, 2)) { nsplit = 2; sa = 3 * M; batched = true; }
    else                                { nsplit = 1; sa = 1 * M; batched = false; }

    unsigned short* ws    = (unsigned short*)d_ws;
    unsigned short* slotA = ws;                 // conv inputs, later numb
    unsigned short* qs    = ws + sa;
    unsigned short* ks    = qs + M;
    unsigned short* vT    = ks + M;
    unsigned short* Wc    = vT + M;             // 3 slots stride WS_
    unsigned short* bc    = Wc + 3 * WS_;       // 3 slots stride 512
    float* denom = (float*)(((uintptr_t)(bc + 3 * 512) + 15) & ~(uintptr_t)15);
    unsigned short* numb = slotA;

    const float qscale = 1.0f / sqrtf(512.0f);

    if (batched) {
        conv_all_kernel<<<dim3(13059), dim3(256), 0, stream>>>(
            Qin, Kin, Vin, Wq, Wk, Wv, bq, bk, bv, slotA, Wc, bc);
        proj_kernel<<<dim3(256, 3), dim3(256), 0, stream>>>(
            slotA, M, 0, Wc, bc, qs, ks, vT, qscale);
    } else {
        conv_wb_kernel<<<dim3(257, 3), dim3(256), 0, stream>>>(Wq, Wk, Wv, bq, bk, bv, Wc, bc);
        const float* Xin[3] = { Qin, Kin, Vin };
        for (int m = 0; m < 3; m++) {
            conv1_kernel<<<dim3(4096), dim3(256), 0, stream>>>(Xin[m], slotA);
            proj_kernel<<<dim3(256, 1), dim3(256), 0, stream>>>(
                slotA, 0, m, Wc, bc, qs, ks, vT, qscale);
        }
    }

    if (nsplit == 4)
        attn_kernel<4><<<dim3(512), dim3(256), 0, stream>>>(qs, ks, vT, numb, denom);
    else if (nsplit == 2)
        attn_kernel<2><<<dim3(256), dim3(256), 0, stream>>>(qs, ks, vT, numb, denom);
    else
        attn_kernel<1><<<dim3(128), dim3(256), 0, stream>>>(qs, ks, vT, numb, denom);

    combine_kernel<<<dim3(2048), dim3(256), 0, stream>>>(
        numb, denom, (float*)d_out, nsplit);
}

// Round 9
// 226.871 us; speedup vs baseline: 1.2325x; 1.2325x over previous
//
#include <hip/hip_runtime.h>
#include <hip/hip_bf16.h>
#include <math.h>
#include <stdint.h>

// ---------- types ----------
typedef __attribute__((ext_vector_type(8))) short short8;     // 8 x bf16 (MFMA A/B frag)
typedef __attribute__((ext_vector_type(4))) float floatx4;    // MFMA C/D frag
typedef __attribute__((ext_vector_type(4))) unsigned short ushort4v;

// ---------- helpers ----------
__device__ __forceinline__ void gload_lds16(const void* g, void* lds) {
    __builtin_amdgcn_global_load_lds(
        (__attribute__((address_space(1))) void*)(g),
        (__attribute__((address_space(3))) void*)(lds), 16, 0, 0);
}
__device__ __forceinline__ float bf16bits_to_f(unsigned short u) {
    union { unsigned int i; float f; } x; x.i = ((unsigned int)u) << 16; return x.f;
}
__device__ __forceinline__ unsigned short f_to_bf16bits(float f) {
    union { float f; unsigned int i; } x; x.f = f;
    unsigned int lsb = (x.i >> 16) & 1u;
    x.i += 0x7fffu + lsb;                      // round-to-nearest-even
    return (unsigned short)(x.i >> 16);
}

// =====================================================================
// One-dispatch fp32->bf16 conversion: Q,K,V (12288 blocks) + W x3 (768) +
// b x3 (3). grid 13059.
// =====================================================================
__global__ __launch_bounds__(256) void conv_all_kernel(
    const float* __restrict__ Q, const float* __restrict__ K, const float* __restrict__ V,
    const float* __restrict__ Wq, const float* __restrict__ Wk, const float* __restrict__ Wv,
    const float* __restrict__ bq, const float* __restrict__ bk, const float* __restrict__ bv,
    unsigned short* __restrict__ qkv,  // 3 slots stride 4194304
    unsigned short* __restrict__ Wo,   // 3 slots stride 262144
    unsigned short* __restrict__ bo)   // 3 slots stride 512
{
    const int gid = blockIdx.x;
    const float* src; unsigned short* dst; int idx;
    if (gid < 12288) {
        const int seg = gid >> 12, blk = gid & 4095;
        src = (seg == 0) ? Q : (seg == 1) ? K : V;
        dst = qkv + (size_t)seg * 4194304;
        idx = (blk * 256 + threadIdx.x) * 4;
    } else if (gid < 13056) {
        const int t = gid - 12288, m = t >> 8, blk = t & 255;
        src = (m == 0) ? Wq : (m == 1) ? Wk : Wv;
        dst = Wo + (size_t)m * 262144;
        idx = (blk * 256 + threadIdx.x) * 4;
    } else {
        const int m = gid - 13056;
        if (threadIdx.x >= 128) return;
        src = (m == 0) ? bq : (m == 1) ? bk : bv;
        dst = bo + (size_t)m * 512;
        idx = threadIdx.x * 4;
    }
    float4 v = *(const float4*)&src[idx];
    ushort4v o;
    o[0] = f_to_bf16bits(v.x); o[1] = f_to_bf16bits(v.y);
    o[2] = f_to_bf16bits(v.z); o[3] = f_to_bf16bits(v.w);
    *(ushort4v*)&dst[idx] = o;
}

// single-input fp32 -> bf16 (small-ws fallback). grid 4096.
__global__ __launch_bounds__(256) void conv1_kernel(
    const float* __restrict__ in, unsigned short* __restrict__ out)
{
    const int idx = (blockIdx.x * 256 + threadIdx.x) * 4;
    float4 v = *(const float4*)&in[idx];
    ushort4v o;
    o[0] = f_to_bf16bits(v.x); o[1] = f_to_bf16bits(v.y);
    o[2] = f_to_bf16bits(v.z); o[3] = f_to_bf16bits(v.w);
    *(ushort4v*)&out[idx] = o;
}

// W/b conversion only (fallback path). grid (257,3).
__global__ __launch_bounds__(256) void conv_wb_kernel(
    const float* __restrict__ Wq, const float* __restrict__ Wk, const float* __restrict__ Wv,
    const float* __restrict__ bq, const float* __restrict__ bk, const float* __restrict__ bv,
    unsigned short* __restrict__ Wo, unsigned short* __restrict__ bo)
{
    const int m = blockIdx.y;
    const float* W = (m == 0) ? Wq : (m == 1) ? Wk : Wv;
    const float* b = (m == 0) ? bq : (m == 1) ? bk : bv;
    if (blockIdx.x < 256) {
        const int idx = (blockIdx.x * 256 + threadIdx.x) * 4;
        float4 v = *(const float4*)&W[idx];
        ushort4v o;
        o[0] = f_to_bf16bits(v.x); o[1] = f_to_bf16bits(v.y);
        o[2] = f_to_bf16bits(v.z); o[3] = f_to_bf16bits(v.w);
        *(ushort4v*)&Wo[(size_t)m * 262144 + idx] = o;
    } else if (threadIdx.x < 128) {
        const int idx = threadIdx.x * 4;
        float4 v = *(const float4*)&b[idx];
        ushort4v o;
        o[0] = f_to_bf16bits(v.x); o[1] = f_to_bf16bits(v.y);
        o[2] = f_to_bf16bits(v.z); o[3] = f_to_bf16bits(v.w);
        *(ushort4v*)&bo[(size_t)m * 512 + idx] = o;
    }
}

// =====================================================================
// Projection: C[m,n] = sum_k X[m,k]*W[n,k] + b[n]. M=8192,N=512,K=512.
// grid (256, nmodes); mode = mode_base + blockIdx.y.
// mode 0: q (scaled), 1: k, 2: v stored in PV-B-frag-native layout:
//   V6 elem(b,d,k) at  b*2097152 + (d>>4)*65536 + (k>>3)*128 + (d&15)*8 + (k&7)
// =====================================================================
__global__ __launch_bounds__(256, 2) void proj_kernel(
    const unsigned short* __restrict__ Xall,
    size_t xstride, int mode_base,
    const unsigned short* __restrict__ Wall,  // 3 slots stride 262144
    const unsigned short* __restrict__ ball,  // 3 slots stride 512
    unsigned short* __restrict__ qbuf,        // [8192,512] pre-scaled
    unsigned short* __restrict__ kbuf,        // [8192,512]
    unsigned short* __restrict__ vTbuf,       // V6 layout, 2*2097152 elems
    float qscale)
{
    __shared__ __align__(16) unsigned short Xs[128 * 64];
    __shared__ __align__(16) unsigned short Ws[128 * 64];

    const int mode = mode_base + blockIdx.y;
    const unsigned short* X = Xall + (size_t)blockIdx.y * xstride;
    const unsigned short* W = Wall + (size_t)mode * 262144;
    const unsigned short* bias = ball + (size_t)mode * 512;

    const int tid = threadIdx.x;
    const int wave = tid >> 6, lane = tid & 63, quad = lane >> 4, l15 = lane & 15;
    const int m0 = (int)(blockIdx.x >> 2) << 7;
    const int n0 = (int)(blockIdx.x & 3) << 7;
    const int mw = (wave >> 1) << 6, nw = (wave & 1) << 6;

    floatx4 acc[4][4];
    #pragma unroll
    for (int i = 0; i < 4; i++)
        #pragma unroll
        for (int j = 0; j < 4; j++) acc[i][j] = floatx4{0.f, 0.f, 0.f, 0.f};

    for (int kt = 0; kt < 512; kt += 64) {
        #pragma unroll
        for (int i = 0; i < 4; i++) {
            const int r0 = wave * 32 + i * 8;
            gload_lds16(X + (size_t)(m0 + r0 + (lane >> 3)) * 512 + kt + (lane & 7) * 8, &Xs[r0 * 64]);
            gload_lds16(W + (size_t)(n0 + r0 + (lane >> 3)) * 512 + kt + (lane & 7) * 8, &Ws[r0 * 64]);
        }
        __syncthreads();
        #pragma unroll
        for (int kk = 0; kk < 64; kk += 32) {
            short8 a[4], b[4];
            #pragma unroll
            for (int i = 0; i < 4; i++) a[i] = *(const short8*)&Xs[(mw + 16 * i + l15) * 64 + kk + quad * 8];
            #pragma unroll
            for (int j = 0; j < 4; j++) b[j] = *(const short8*)&Ws[(nw + 16 * j + l15) * 64 + kk + quad * 8];
            #pragma unroll
            for (int i = 0; i < 4; i++)
                #pragma unroll
                for (int j = 0; j < 4; j++)
                    acc[i][j] = __builtin_amdgcn_mfma_f32_16x16x32_bf16(a[i], b[j], acc[i][j], 0, 0, 0);
        }
        __syncthreads();
    }

    float bfj[4];
    #pragma unroll
    for (int j = 0; j < 4; j++) bfj[j] = bf16bits_to_f(bias[n0 + nw + 16 * j + l15]);

    if (mode < 2) {
        unsigned short* out = (mode == 0) ? qbuf : kbuf;
        const float s = (mode == 0) ? qscale : 1.0f;
        #pragma unroll
        for (int i = 0; i < 4; i++) {
            const int mrow = m0 + mw + 16 * i + quad * 4;   // C/D: row = quad*4+reg
            #pragma unroll
            for (int j = 0; j < 4; j++) {
                const int n = n0 + nw + 16 * j + l15;       // C/D: col = lane&15
                #pragma unroll
                for (int r = 0; r < 4; r++)
                    out[(size_t)(mrow + r) * 512 + n] = f_to_bf16bits((acc[i][j][r] + bfj[j]) * s);
            }
        }
    } else {
        // V6 layout: 4 consecutive keys -> 8B store
        #pragma unroll
        for (int i = 0; i < 4; i++) {
            const int mrow = m0 + mw + 16 * i + quad * 4;
            const int bb = mrow >> 12;
            const int k4 = mrow & 4095;
            const size_t kpart = (size_t)bb * 2097152 + (size_t)(k4 >> 3) * 128 + (k4 & 7);
            #pragma unroll
            for (int j = 0; j < 4; j++) {
                const int n = n0 + nw + 16 * j + l15;
                ushort4v pk;
                #pragma unroll
                for (int r = 0; r < 4; r++) pk[r] = f_to_bf16bits(acc[i][j][r] + bfj[j]);
                *(ushort4v*)&vTbuf[kpart + (size_t)(n >> 4) * 65536 + (n & 15) * 8] = pk;
            }
        }
    }
}

// =====================================================================
// Flash attention v6: S-phase d-split reuse-2, spill-free.
// Wave (mgrp=w>>1, dh=w&1): S-partials for rows [32*mgrp,+32) x 32 keys over
// d-half [256*dh,+256). S-accumulators are NAMED registers (s00..s11) and the
// partner exchange uses a wave-uniform static branch on dh — no dynamic
// register-array indexing (r8's scratch-spill bug).
// PV: wave w owns d-cols [128w,+128), V frags direct from global (V6 layout).
// 3 barriers/iter. denom has 2*NSPLIT slots.
// =====================================================================
template <int NSPLIT>
__global__ __launch_bounds__(256, 2) void attn_kernel(
    const unsigned short* __restrict__ q,    // [8192,512] pre-scaled
    const unsigned short* __restrict__ k,    // [8192,512]
    const unsigned short* __restrict__ vT,   // V6 layout
    unsigned short* __restrict__ num,        // [NSPLIT,8192,512] permuted bf16 partials
    float* __restrict__ denom)               // [2*NSPLIT,8192]
{
    constexpr int TK  = 32;
    constexpr int KST = 520;   // 512 + 8 pad
    constexpr int PST = 40;    // 32 + 8 pad
    __shared__ __align__(16) unsigned short Ks[TK * KST];       // 33.3 KB
    __shared__ __align__(16) unsigned short Ps[64 * PST];       // 5 KB
    __shared__ __align__(16) float Xch[2][2][2][64][4];         // [mgrp][keyhalf][i2][lane] 8 KB

    const int tid = threadIdx.x;
    const int wave = tid >> 6, lane = tid & 63, quad = lane >> 4, l15 = lane & 15;
    const int mgrp = wave >> 1, dh = wave & 1;
    const int bid = blockIdx.x;
    const int sp   = bid & (NSPLIT - 1);
    const int qblk = bid / NSPLIT;
    const int bb = qblk >> 6;              // batch
    const int q0 = (qblk & 63) << 6;       // q-tile start within batch
    const size_t rowbase = (size_t)bb * 4096 + q0;

    // Q fragments: rows 32*mgrp + 16*i2 + l15, d in [256*dh, 256*dh+256)
    short8 qf[16];
    {
        const unsigned short* qbase = q + (rowbase + 32 * mgrp + l15) * 512 + dh * 256;
        #pragma unroll
        for (int i2 = 0; i2 < 2; i2++)
            #pragma unroll
            for (int t = 0; t < 8; t++)
                qf[i2 * 8 + t] = *(const short8*)&qbase[i2 * 16 * 512 + t * 32 + quad * 8];
    }

    floatx4 oacc[4][8];                    // rows 16i+quad*4+r, cols 128*wave+16c+l15
    #pragma unroll
    for (int i = 0; i < 4; i++)
        #pragma unroll
        for (int c = 0; c < 8; c++) oacc[i][c] = floatx4{0.f, 0.f, 0.f, 0.f};
    float dsum[2][4];                      // [i2][r] partial denom (this wave's 16 keys)
    #pragma unroll
    for (int i2 = 0; i2 < 2; i2++)
        #pragma unroll
        for (int r = 0; r < 4; r++) dsum[i2][r] = 0.f;

    const unsigned short* kb = k + (size_t)bb * 4096 * 512;
    const unsigned short* vbase = vT + (size_t)bb * 2097152
                                + (size_t)(8 * wave) * 65536 + quad * 128 + l15 * 8;

    const int jbeg = sp * (4096 / NSPLIT);
    const int jend = jbeg + (4096 / NSPLIT);
    for (int j0 = jbeg; j0 < jend; j0 += TK) {
        // --- stage K tile (32 rows x 512) async ---
        #pragma unroll
        for (int r = 0; r < 8; r++) {
            const int row = wave * 8 + r;                       // one 1KB row per issue
            gload_lds16(kb + (size_t)(j0 + row) * 512 + lane * 8, &Ks[row * KST]);
        }
        __syncthreads();   // B1: K staged (implicit vmcnt0)

        // --- V fragments: coalesced 1KB loads, land during S-phase ---
        short8 vf[8];
        #pragma unroll
        for (int c = 0; c < 8; c++)
            vf[c] = *(const short8*)&vbase[(size_t)c * 65536 + (j0 << 4)];

        // --- S-partials: 32 rows x 32 keys over this wave's d-half ---
        // s<i2><c>: rows 32mgrp+16i2+quad*4+r, keys c*16+l15 (named regs, no arrays)
        floatx4 s00 = floatx4{0.f, 0.f, 0.f, 0.f};
        floatx4 s01 = s00, s10 = s00, s11 = s00;
        #pragma unroll
        for (int t = 0; t < 8; t++) {
            short8 b0 = *(const short8*)&Ks[(     l15) * KST + dh * 256 + t * 32 + quad * 8];
            short8 b1 = *(const short8*)&Ks[(16 + l15) * KST + dh * 256 + t * 32 + quad * 8];
            s00 = __builtin_amdgcn_mfma_f32_16x16x32_bf16(qf[t],     b0, s00, 0, 0, 0);
            s01 = __builtin_amdgcn_mfma_f32_16x16x32_bf16(qf[t],     b1, s01, 0, 0, 0);
            s10 = __builtin_amdgcn_mfma_f32_16x16x32_bf16(qf[8 + t], b0, s10, 0, 0, 0);
            s11 = __builtin_amdgcn_mfma_f32_16x16x32_bf16(qf[8 + t], b1, s11, 0, 0, 0);
        }

        // --- exchange: static-branch select (dh is wave-uniform) ---
        floatx4 oth0, oth1, mine0, mine1;
        if (dh == 0) { oth0 = s01; oth1 = s11; mine0 = s00; mine1 = s10; }
        else         { oth0 = s00; oth1 = s10; mine0 = s01; mine1 = s11; }
        *(floatx4*)&Xch[mgrp][dh ^ 1][0][lane][0] = oth0;
        *(floatx4*)&Xch[mgrp][dh ^ 1][1][lane][0] = oth1;
        __syncthreads();   // B2: partner partials visible
        {
            floatx4 p0 = *(const floatx4*)&Xch[mgrp][dh][0][lane][0];
            floatx4 p1 = *(const floatx4*)&Xch[mgrp][dh][1][lane][0];
            #pragma unroll
            for (int r = 0; r < 4; r++) { mine0[r] += p0[r]; mine1[r] += p1[r]; }
        }

        // --- exp own 16-key half, write Ps ---
        #pragma unroll
        for (int r = 0; r < 4; r++) {
            const float pa = __expf(fminf(mine0[r], 30.0f));
            const unsigned short pba = f_to_bf16bits(pa);
            dsum[0][r] += bf16bits_to_f(pba);
            Ps[(32 * mgrp + quad * 4 + r) * PST + dh * 16 + l15] = pba;
            const float pb = __expf(fminf(mine1[r], 30.0f));
            const unsigned short pbb = f_to_bf16bits(pb);
            dsum[1][r] += bf16bits_to_f(pbb);
            Ps[(32 * mgrp + 16 + quad * 4 + r) * PST + dh * 16 + l15] = pbb;
        }
        __syncthreads();   // B3: Ps complete before cross-wave A-frag reads

        // --- O[0:64][128w:128w+128] += P @ V (A from LDS, B from regs) ---
        short8 ap[4];
        #pragma unroll
        for (int i = 0; i < 4; i++) ap[i] = *(const short8*)&Ps[(16 * i + l15) * PST + quad * 8];
        #pragma unroll
        for (int c = 0; c < 8; c++) {
            #pragma unroll
            for (int i = 0; i < 4; i++)
                oacc[i][c] = __builtin_amdgcn_mfma_f32_16x16x32_bf16(ap[i], vf[c], oacc[i][c], 0, 0, 0);
        }
        // no 4th barrier: next B1/B2 order Ks-DMA and Xch/Ps hazards
    }

    // denom: reduce each (i2,r) row-partial across the 16 l15 lanes
    #pragma unroll
    for (int i2 = 0; i2 < 2; i2++) {
        #pragma unroll
        for (int r = 0; r < 4; r++) {
            float v = dsum[i2][r];
            v += __shfl_xor(v, 1);
            v += __shfl_xor(v, 2);
            v += __shfl_xor(v, 4);
            v += __shfl_xor(v, 8);
            if (l15 == 0) {
                const size_t row = rowbase + 32 * mgrp + 16 * i2 + quad * 4 + r;
                denom[(size_t)(sp * 2 + dh) * 8192 + row] = v;
            }
        }
    }

    // store bf16 numerator partials, permuted: [row][wave][l15][c] -> b128
    #pragma unroll
    for (int i = 0; i < 4; i++) {
        #pragma unroll
        for (int r = 0; r < 4; r++) {
            const size_t row = rowbase + 16 * i + quad * 4 + r;
            short8 pk;
            #pragma unroll
            for (int c = 0; c < 8; c++) pk[c] = (short)f_to_bf16bits(oacc[i][c][r]);
            *(short8*)&num[((size_t)sp * 8192 + row) * 512 + wave * 128 + l15 * 8] = pk;
        }
    }
}

// =====================================================================
// Combine: out = (sum_sp num) / (sum over 2*nsplit denom slots), fp32 out.
// thread = (srow, w, l15); reads permuted num as b128.
// =====================================================================
__global__ __launch_bounds__(256) void combine_kernel(
    const unsigned short* __restrict__ num,
    const float* __restrict__ denom,
    float* __restrict__ out,
    int nsplit)
{
    const int gid = blockIdx.x * 256 + threadIdx.x;
    const int srow = gid >> 6;            // 0..8191
    const int sub = gid & 63;
    const int w = sub >> 4, l15 = sub & 15;
    float s[8];
    #pragma unroll
    for (int e = 0; e < 8; e++) s[e] = 0.f;
    float den = 0.f;
    for (int sp = 0; sp < 2 * nsplit; sp++)
        den += denom[(size_t)sp * 8192 + srow];
    for (int sp = 0; sp < nsplit; sp++) {
        short8 v = *(const short8*)(num + ((size_t)sp * 8192 + srow) * 512 + w * 128 + l15 * 8);
        #pragma unroll
        for (int e = 0; e < 8; e++) s[e] += bf16bits_to_f((unsigned short)v[e]);
    }
    const float inv = 1.0f / den;
    float* op = out + (size_t)srow * 512 + w * 128 + l15;
    #pragma unroll
    for (int c = 0; c < 8; c++) op[16 * c] = s[c] * inv;
}

// =====================================================================
extern "C" void kernel_launch(void* const* d_in, const int* in_sizes, int n_in,
                              void* d_out, int out_size, void* d_ws, size_t ws_size,
                              hipStream_t stream)
{
    (void)in_sizes; (void)n_in; (void)out_size;
    const float* Qin = (const float*)d_in[0];
    const float* Kin = (const float*)d_in[1];
    const float* Vin = (const float*)d_in[2];
    const float* Wq  = (const float*)d_in[3];
    const float* bq  = (const float*)d_in[4];
    const float* Wk  = (const float*)d_in[5];
    const float* bk  = (const float*)d_in[6];
    const float* Wv  = (const float*)d_in[7];
    const float* bv  = (const float*)d_in[8];

    const size_t M   = (size_t)8192 * 512;   // 4,194,304 elems
    const size_t WS_ = (size_t)512 * 512;

    // ws layout (bf16 elems): [slotA: conv inputs / num partials][qs][ks][vT][Wc x3][bc x3][denom f32 x 2ns]
    auto need = [&](size_t sa, int ns) -> size_t {
        return (sa + 3 * M) * 2 + 3 * WS_ * 2 + 3 * 512 * 2 + 64 + (size_t)ns * 2 * 8192 * 4;
    };
    int nsplit; size_t sa; bool batched;
    if      (ws_size >= need(4 * M, 4)) { nsplit = 4; sa = 4 * M; batched = true; }
    else if (ws_size >= need(3 * M, 2)) { nsplit = 2; sa = 3 * M; batched = true; }
    else                                { nsplit = 1; sa = 1 * M; batched = false; }

    unsigned short* ws    = (unsigned short*)d_ws;
    unsigned short* slotA = ws;                 // conv inputs, later numb
    unsigned short* qs    = ws + sa;
    unsigned short* ks    = qs + M;
    unsigned short* vT    = ks + M;
    unsigned short* Wc    = vT + M;             // 3 slots stride WS_
    unsigned short* bc    = Wc + 3 * WS_;       // 3 slots stride 512
    float* denom = (float*)(((uintptr_t)(bc + 3 * 512) + 15) & ~(uintptr_t)15);
    unsigned short* numb = slotA;

    const float qscale = 1.0f / sqrtf(512.0f);

    if (batched) {
        conv_all_kernel<<<dim3(13059), dim3(256), 0, stream>>>(
            Qin, Kin, Vin, Wq, Wk, Wv, bq, bk, bv, slotA, Wc, bc);
        proj_kernel<<<dim3(256, 3), dim3(256), 0, stream>>>(
            slotA, M, 0, Wc, bc, qs, ks, vT, qscale);
    } else {
        conv_wb_kernel<<<dim3(257, 3), dim3(256), 0, stream>>>(Wq, Wk, Wv, bq, bk, bv, Wc, bc);
        const float* Xin[3] = { Qin, Kin, Vin };
        for (int m = 0; m < 3; m++) {
            conv1_kernel<<<dim3(4096), dim3(256), 0, stream>>>(Xin[m], slotA);
            proj_kernel<<<dim3(256, 1), dim3(256), 0, stream>>>(
                slotA, 0, m, Wc, bc, qs, ks, vT, qscale);
        }
    }

    if (nsplit == 4)
        attn_kernel<4><<<dim3(512), dim3(256), 0, stream>>>(qs, ks, vT, numb, denom);
    else if (nsplit == 2)
        attn_kernel<2><<<dim3(256), dim3(256), 0, stream>>>(qs, ks, vT, numb, denom);
    else
        attn_kernel<1><<<dim3(128), dim3(256), 0, stream>>>(qs, ks, vT, numb, denom);

    combine_kernel<<<dim3(2048), dim3(256), 0, stream>>>(
        numb, denom, (float*)d_out, nsplit);
}